// Round 2
// baseline (203.163 us; speedup 1.0000x reference)
//
#include <hip/hip_runtime.h>
#include <math.h>

#define BATCH 8
#define HW_N 409600          // 640*640
#define HW4 (HW_N / 4)       // 102400
#define NCH 4
#define NSEG 9

// K1 per-batch accumulator layout
#define N_K1 59
#define I_AK   0
#define I_BK   1
#define I_CK   2
#define I_POS  3
#define I_NEG  4
#define I_CNTK 5             // +s (9)
#define I_CNTT 14            // +s (9)
#define I_SUMK 23            // +s*4+c (36)

// K5 per-batch accumulator layout: 0=at 1=bt 2=ct, 3+s = sum_l[s]
#define N_K5 12

#define HIST_BINS 65536
#define HIST_BYTES ((size_t)BATCH * HIST_BINS * 4)

__device__ __forceinline__ unsigned f2key(float x) {
    unsigned u = __float_as_uint(x);
    return (u & 0x80000000u) ? ~u : (u | 0x80000000u);
}
__device__ __forceinline__ float key2f(unsigned k) {
    unsigned u = (k & 0x80000000u) ? (k & 0x7fffffffu) : ~k;
    return __uint_as_float(u);
}
__device__ __forceinline__ float wred64(float v) {
#pragma unroll
    for (int o = 32; o > 0; o >>= 1) v += __shfl_xor(v, o, 64);
    return v;
}
__device__ __forceinline__ float f4c(const float4& v, int p) {
    return p == 0 ? v.x : p == 1 ? v.y : p == 2 ? v.z : v.w;
}
__device__ __forceinline__ int i4c(const int4& v, int p) {
    return p == 0 ? v.x : p == 1 ? v.y : p == 2 ? v.z : v.w;
}

// ---------------------------------------------------------------------------
// K1: main per-pixel reduce (vectorized float4, exactly one iteration/thread)
// ---------------------------------------------------------------------------
__global__ __launch_bounds__(256)
void k1_main(const float4* __restrict__ Tl, const float4* __restrict__ Kl,
             const float4* __restrict__ Fv, const float4* __restrict__ Gt,
             const float4* __restrict__ Gk, const float4* __restrict__ Tm,
             const int4* __restrict__ Ltk, const int4* __restrict__ Lkk,
             unsigned* __restrict__ hist, float* __restrict__ k1s) {
    const int b = blockIdx.y;
    const long base4 = (long)b * HW4;
    const long f04 = (long)b * NCH * HW4;
    unsigned* hb = hist + (size_t)b * HIST_BINS;
    const int i4 = blockIdx.x * blockDim.x + threadIdx.x;   // < HW4 exactly

    float r[N_K1];
#pragma unroll
    for (int j = 0; j < N_K1; j++) r[j] = 0.f;

    const float4 tl4 = Tl[base4 + i4];
    const float4 kl4 = Kl[base4 + i4];
    const float4 gt4 = Gt[base4 + i4];
    const float4 gk4 = Gk[base4 + i4];
    const float4 tm4 = Tm[base4 + i4];
    const int4 ltk4 = Ltk[base4 + i4];
    const int4 lkk4 = Lkk[base4 + i4];
    const float4 F0v = Fv[f04 + i4];
    const float4 F1v = Fv[f04 + HW4 + i4];
    const float4 F2v = Fv[f04 + 2 * HW4 + i4];
    const float4 F3v = Fv[f04 + 3 * HW4 + i4];

#pragma unroll
    for (int p = 0; p < 4; p++) {
        float tl = f4c(tl4, p), kl = f4c(kl4, p);
        float gt = f4c(gt4, p), gk = f4c(gk4, p), m = f4c(tm4, p);
        int ltk_v = i4c(ltk4, p), lkk_v = i4c(lkk4, p);
        float F0 = f4c(F0v, p), F1 = f4c(F1v, p), F2 = f4c(F2v, p), F3 = f4c(F3v, p);

        bool tm = m > 0.5f;
        bool selt = tl > 0.0f;          // sigmoid(x) > 0.5  <=>  x > 0
        bool selk = kl > 0.0f;
        float km = (selt && tm) ? 1.f : 0.f;

        float pk = 1.f / (1.f + __expf(-kl));
        r[I_AK] = fmaf(pk * gk, km, r[I_AK]);
        r[I_BK] = fmaf(pk * pk, km, r[I_BK]);
        r[I_CK] = fmaf(gk * gk, km, r[I_CK]);

        bool pos = gt > 0.5f;
        r[I_POS] += (pos && tm) ? 1.f : 0.f;
        if (!pos) {
            r[I_NEG] += 1.f;
            atomicAdd(&hb[f2key(tl) >> 16], 1u);
        }

        int lt = (selt && tm) ? ltk_v : 0;
        int lk = (selk && tm) ? lkk_v : 0;
#pragma unroll
        for (int s = 0; s < NSEG; s++) {
            float fek = (lk == s) ? 1.f : 0.f;
            float fet = (lt == s) ? 1.f : 0.f;
            r[I_CNTK + s] += fek;
            r[I_CNTT + s] += fet;
            r[I_SUMK + s * 4 + 0] = fmaf(fek, F0, r[I_SUMK + s * 4 + 0]);
            r[I_SUMK + s * 4 + 1] = fmaf(fek, F1, r[I_SUMK + s * 4 + 1]);
            r[I_SUMK + s * 4 + 2] = fmaf(fek, F2, r[I_SUMK + s * 4 + 2]);
            r[I_SUMK + s * 4 + 3] = fmaf(fek, F3, r[I_SUMK + s * 4 + 3]);
        }
    }

#pragma unroll
    for (int j = 0; j < N_K1; j++) r[j] = wred64(r[j]);

    __shared__ float bacc[N_K1];
    for (int j = threadIdx.x; j < N_K1; j += blockDim.x) bacc[j] = 0.f;
    __syncthreads();
    if ((threadIdx.x & 63) == 0) {
#pragma unroll
        for (int j = 0; j < N_K1; j++) atomicAdd(&bacc[j], r[j]);
    }
    __syncthreads();
    for (int j = threadIdx.x; j < N_K1; j += blockDim.x)
        atomicAdd(&k1s[b * N_K1 + j], bacc[j]);
}

// ---------------------------------------------------------------------------
// K2: per-batch: k = min(3*pos, neg); find hi-16 bin of the k-th largest
// negative logit. uint4 chunk loads.
// ---------------------------------------------------------------------------
__global__ __launch_bounds__(256)
void k2_selhi(const unsigned* __restrict__ hist, const float* __restrict__ k1s,
              float* thr, unsigned* kval, unsigned* binhi, unsigned* cntb,
              unsigned* fb) {
    const int b = blockIdx.x;
    const int t = threadIdx.x;
    const unsigned* hb = hist + (size_t)b * HIST_BINS;

    unsigned pos = (unsigned)(k1s[b * N_K1 + I_POS] + 0.5f);
    unsigned neg = (unsigned)(k1s[b * N_K1 + I_NEG] + 0.5f);
    unsigned k = min(3u * pos, neg);
    if (t == 0) kval[b] = k;
    if (pos == 0u || k == 0u) {
        if (t == 0) { fb[b] = 1u; thr[b] = -INFINITY; }
        return;
    }
    if (t == 0) fb[b] = 0u;

    const int lo = 65280 - t * 256;          // chunk [lo, lo+255], t=0 topmost
    const uint4* h4 = (const uint4*)(hb + lo);
    unsigned csum = 0;
#pragma unroll 4
    for (int i = 0; i < 64; i++) {
        uint4 v = h4[i];
        csum += v.x + v.y + v.z + v.w;
    }

    __shared__ unsigned pref[256];
    pref[t] = csum;
    __syncthreads();
    for (int o = 1; o < 256; o <<= 1) {
        unsigned v = (t >= o) ? pref[t - o] : 0u;
        __syncthreads();
        pref[t] += v;
        __syncthreads();
    }
    unsigned incl = pref[t];
    unsigned excl = incl - csum;
    if (excl < k && incl >= k) {
        unsigned cum = excl;
        for (int i = 255; i >= 0; --i) {     // descending within chunk
            unsigned h = hb[lo + i];
            cum += h;
            if (cum >= k) {
                binhi[b] = (unsigned)(lo + i);
                cntb[b] = cum - h;
                break;
            }
        }
    }
}

// ---------------------------------------------------------------------------
// K3: low-16 histogram for pixels whose key falls in the selected hi bin.
// ---------------------------------------------------------------------------
__global__ __launch_bounds__(256)
void k3_histlo(const float4* __restrict__ Tl, const float4* __restrict__ Gt,
               const unsigned* __restrict__ binhi, const unsigned* __restrict__ fb,
               unsigned* __restrict__ hist) {
    const int b = blockIdx.y;
    if (fb[b]) return;
    const unsigned target = binhi[b];
    const long base4 = (long)b * HW4;
    unsigned* hb = hist + (size_t)b * HIST_BINS;
    const int i4 = blockIdx.x * blockDim.x + threadIdx.x;
    const float4 gt4 = Gt[base4 + i4];
    const float4 tl4 = Tl[base4 + i4];
#pragma unroll
    for (int p = 0; p < 4; p++) {
        if (f4c(gt4, p) > 0.5f) continue;
        unsigned key = f2key(f4c(tl4, p));
        if ((key >> 16) == target) atomicAdd(&hb[key & 0xFFFFu], 1u);
    }
}

// ---------------------------------------------------------------------------
// K4: per-batch: exact threshold key within the hi bin.
// ---------------------------------------------------------------------------
__global__ __launch_bounds__(256)
void k4_sello(const unsigned* __restrict__ hist, const unsigned* __restrict__ kval,
              const unsigned* __restrict__ binhi, const unsigned* __restrict__ cntb,
              const unsigned* __restrict__ fb, float* thr) {
    const int b = blockIdx.x;
    if (fb[b]) return;
    const int t = threadIdx.x;
    const unsigned* hb = hist + (size_t)b * HIST_BINS;
    unsigned j = kval[b] - cntb[b];          // j-th largest within the bin, >=1

    const int lo = 65280 - t * 256;
    const uint4* h4 = (const uint4*)(hb + lo);
    unsigned csum = 0;
#pragma unroll 4
    for (int i = 0; i < 64; i++) {
        uint4 v = h4[i];
        csum += v.x + v.y + v.z + v.w;
    }

    __shared__ unsigned pref[256];
    pref[t] = csum;
    __syncthreads();
    for (int o = 1; o < 256; o <<= 1) {
        unsigned v = (t >= o) ? pref[t - o] : 0u;
        __syncthreads();
        pref[t] += v;
        __syncthreads();
    }
    unsigned incl = pref[t];
    unsigned excl = incl - csum;
    if (excl < j && incl >= j) {
        unsigned cum = excl;
        for (int i = 255; i >= 0; --i) {
            unsigned h = hb[lo + i];
            cum += h;
            if (cum >= j) {
                thr[b] = key2f((binhi[b] << 16) | (unsigned)(lo + i));
                break;
            }
        }
    }
}

// ---------------------------------------------------------------------------
// K5: text dice sums with OHEM mask + aggregation-loss segment sums.
// ---------------------------------------------------------------------------
__global__ __launch_bounds__(256)
void k5_textagg(const float4* __restrict__ Tl, const float4* __restrict__ Gt,
                const float4* __restrict__ Tm, const int4* __restrict__ Ltk,
                const float4* __restrict__ Fv, const float* __restrict__ k1s,
                const float* __restrict__ thr, float* __restrict__ k5s) {
    const int b = blockIdx.y;
    __shared__ float Km[NSEG * NCH];
    if (threadIdx.x < NSEG * NCH) {
        int s = threadIdx.x >> 2, c = threadIdx.x & 3;
        Km[threadIdx.x] = k1s[b * N_K1 + I_SUMK + s * 4 + c] /
                          fmaxf(k1s[b * N_K1 + I_CNTK + s], 1.f);
    }
    __syncthreads();
    const float thr_b = thr[b];
    const long base4 = (long)b * HW4;
    const long f04 = (long)b * NCH * HW4;
    const int i4 = blockIdx.x * blockDim.x + threadIdx.x;

    float r[N_K5];
#pragma unroll
    for (int j = 0; j < N_K5; j++) r[j] = 0.f;

    const float4 tl4 = Tl[base4 + i4];
    const float4 gt4 = Gt[base4 + i4];
    const float4 tm4 = Tm[base4 + i4];
    const int4 ltk4 = Ltk[base4 + i4];
    const float4 F0v = Fv[f04 + i4];
    const float4 F1v = Fv[f04 + HW4 + i4];
    const float4 F2v = Fv[f04 + 2 * HW4 + i4];
    const float4 F3v = Fv[f04 + 3 * HW4 + i4];

#pragma unroll
    for (int p = 0; p < 4; p++) {
        float tl = f4c(tl4, p), gt = f4c(gt4, p), m = f4c(tm4, p);
        int ltk_v = i4c(ltk4, p);

        bool tm = m > 0.5f;
        bool pos = gt > 0.5f;
        float om = (((tl >= thr_b) || pos) && tm) ? 1.f : 0.f;
        float pt = 1.f / (1.f + __expf(-tl));
        r[0] = fmaf(pt * gt, om, r[0]);
        r[1] = fmaf(pt * pt, om, r[1]);
        r[2] = fmaf(gt * gt, om, r[2]);

        int lt = (tl > 0.f && tm) ? ltk_v : 0;
        if (lt > 0) {
            float d0 = f4c(F0v, p) - Km[lt * 4 + 0];
            float d1 = f4c(F1v, p) - Km[lt * 4 + 1];
            float d2 = f4c(F2v, p) - Km[lt * 4 + 2];
            float d3 = f4c(F3v, p) - Km[lt * 4 + 3];
            float d = sqrtf(d0 * d0 + d1 * d1 + d2 * d2 + d3 * d3);
            float tt = fmaxf(d - 0.5f, 0.f);
            float pl = __logf(tt * tt + 1.f);
#pragma unroll
            for (int s = 1; s < NSEG; s++)
                r[3 + s] = fmaf((lt == s) ? 1.f : 0.f, pl, r[3 + s]);
        }
    }

#pragma unroll
    for (int j = 0; j < N_K5; j++) r[j] = wred64(r[j]);

    __shared__ float bacc[N_K5];
    if (threadIdx.x < N_K5) bacc[threadIdx.x] = 0.f;
    __syncthreads();
    if ((threadIdx.x & 63) == 0) {
#pragma unroll
        for (int j = 0; j < N_K5; j++) atomicAdd(&bacc[j], r[j]);
    }
    __syncthreads();
    if (threadIdx.x < N_K5)
        atomicAdd(&k5s[b * N_K5 + threadIdx.x], bacc[threadIdx.x]);
}

// ---------------------------------------------------------------------------
// K6: final combine -> scalar loss.
// ---------------------------------------------------------------------------
__global__ __launch_bounds__(512)
void k6_final(const float* __restrict__ k1s, const float* __restrict__ k5s,
              float* __restrict__ out) {
    const int tid = threadIdx.x;
    const int b = tid >> 6, lane = tid & 63;
    __shared__ float Km[BATCH][NSEG][NCH];
    __shared__ float laS[BATCH], ldS[BATCH];

    if (tid < BATCH * NSEG * NCH) {
        int bb = tid / (NSEG * NCH);
        int rem = tid % (NSEG * NCH);
        int s = rem >> 2, c = rem & 3;
        Km[bb][s][c] = k1s[bb * N_K1 + I_SUMK + s * 4 + c] /
                       fmaxf(k1s[bb * N_K1 + I_CNTK + s], 1.f);
    }
    __syncthreads();

    const float* s1 = k1s + b * N_K1;
    const float* s5 = k5s + b * N_K5;

    float aggs = 0.f, aggc = 0.f;
    if (lane > 0 && lane < NSEG) {
        float ct = s1[I_CNTT + lane], ck = s1[I_CNTK + lane];
        if (ct > 0.f && ck > 0.f) {
            aggs = s5[3 + lane] / fmaxf(ct, 1.f);
            aggc = 1.f;
        }
    }
    float diss = 0.f, disc = 0.f;
    for (int p = lane; p < NSEG * NSEG; p += 64) {
        int i = p / NSEG, j = p % NSEG;
        if (i != j && i > 0 && j > 0 && s1[I_CNTK + i] > 0.f &&
            s1[I_CNTK + j] > 0.f) {
            float d2 = 0.f;
#pragma unroll
            for (int c = 0; c < NCH; c++) {
                float df = Km[b][i][c] - Km[b][j][c];
                d2 += df * df;
            }
            float kd = sqrtf(d2);
            float t = fmaxf(3.0f - kd, 0.f);
            diss += logf(t * t + 1.f);
            disc += 1.f;
        }
    }
    aggs = wred64(aggs);
    aggc = wred64(aggc);
    diss = wred64(diss);
    disc = wred64(disc);
    if (lane == 0) {
        laS[b] = aggs / fmaxf(aggc, 1.f);
        ldS[b] = diss / fmaxf(disc, 1.f);
    }
    __syncthreads();

    if (tid == 0) {
        float Ltx = 0.f, Lk = 0.f, La = 0.f, Ld = 0.f;
        for (int bb = 0; bb < BATCH; bb++) {
            const float* a1 = k1s + bb * N_K1;
            const float* a5 = k5s + bb * N_K5;
            Lk += 1.f - 2.f * a1[I_AK] / ((a1[I_BK] + 1e-6f) + (a1[I_CK] + 1e-6f));
            Ltx += 1.f - 2.f * a5[0] / ((a5[1] + 1e-6f) + (a5[2] + 1e-6f));
            La += laS[bb];
            Ld += ldS[bb];
        }
        out[0] = Ltx / BATCH + 0.5f * (Lk / BATCH) + 0.25f * (La / BATCH + Ld / BATCH);
    }
}

// ---------------------------------------------------------------------------
extern "C" void kernel_launch(void* const* d_in, const int* in_sizes, int n_in,
                              void* d_out, int out_size, void* d_ws, size_t ws_size,
                              hipStream_t stream) {
    (void)in_sizes; (void)n_in; (void)out_size; (void)ws_size;
    const float4* Tl = (const float4*)d_in[0];
    const float4* Kl = (const float4*)d_in[1];
    const float4* Fv = (const float4*)d_in[2];
    const float4* Gt = (const float4*)d_in[3];
    const float4* Gk = (const float4*)d_in[4];
    const float4* Tm = (const float4*)d_in[5];
    const int4* Ltk = (const int4*)d_in[6];
    const int4* Lkk = (const int4*)d_in[7];
    float* out = (float*)d_out;

    unsigned char* wsb = (unsigned char*)d_ws;
    unsigned* hist = (unsigned*)wsb;                       // B*65536 u32
    float* k1s = (float*)(wsb + HIST_BYTES);               // B*59 f32
    float* k5s = k1s + BATCH * N_K1;                       // B*12 f32
    float* thr = k5s + BATCH * N_K5;                       // B f32
    unsigned* kval = (unsigned*)(thr + BATCH);             // B u32
    unsigned* binhi = kval + BATCH;
    unsigned* cntb = binhi + BATCH;
    unsigned* fb = cntb + BATCH;

    size_t zero_bytes = HIST_BYTES +
                        (size_t)(BATCH * (N_K1 + N_K5 + 1)) * 4 +
                        (size_t)BATCH * 4 * 4;
    hipMemsetAsync(d_ws, 0, zero_bytes, stream);

    dim3 g(HW4 / 256, BATCH);   // (400, 8): exactly one float4 per thread
    k1_main<<<g, 256, 0, stream>>>(Tl, Kl, Fv, Gt, Gk, Tm, Ltk, Lkk, hist, k1s);
    k2_selhi<<<BATCH, 256, 0, stream>>>(hist, k1s, thr, kval, binhi, cntb, fb);
    hipMemsetAsync(hist, 0, HIST_BYTES, stream);
    k3_histlo<<<g, 256, 0, stream>>>(Tl, Gt, binhi, fb, hist);
    k4_sello<<<BATCH, 256, 0, stream>>>(hist, kval, binhi, cntb, fb, thr);
    k5_textagg<<<g, 256, 0, stream>>>(Tl, Gt, Tm, Ltk, Fv, k1s, thr, k5s);
    k6_final<<<1, 512, 0, stream>>>(k1s, k5s, out);
}

// Round 3
// 93.646 us; speedup vs baseline: 2.1695x; 2.1695x over previous
//
#include <hip/hip_runtime.h>
#include <math.h>

#define BATCH 8
#define HW_N 409600          // 640*640
#define HW4 (HW_N / 4)       // 102400
#define NCH 4

// k1s per-batch layout (floats)
#define N_K1 53
#define I_AK   0
#define I_BK   1
#define I_CK   2
#define I_POS  3
#define I_NEG  4
#define I_CNTK 5             // +(s-1), s=1..8
#define I_CNTT 13            // +(s-1)
#define I_SUMK 21            // +(s-1)*4+c  (32)

// k5s per-batch layout: 0=at 1=bt 2=ct, 3+s = sum_l[s] (s=1..8 -> 4..11)
#define N_K5 12

#define K1_BLOCKS 200        // per batch: 512 float4 per block, 2 per thread

__device__ __forceinline__ unsigned f2key(float x) {
    unsigned u = __float_as_uint(x);
    return (u & 0x80000000u) ? ~u : (u | 0x80000000u);
}
__device__ __forceinline__ float key2f(unsigned k) {
    unsigned u = (k & 0x80000000u) ? (k & 0x7fffffffu) : ~k;
    return __uint_as_float(u);
}
__device__ __forceinline__ float wred64(float v) {
#pragma unroll
    for (int o = 32; o > 0; o >>= 1) v += __shfl_xor(v, o, 64);
    return v;
}
__device__ __forceinline__ float wredmin64(float v) {
#pragma unroll
    for (int o = 32; o > 0; o >>= 1) v = fminf(v, __shfl_xor(v, o, 64));
    return v;
}
__device__ __forceinline__ float f4c(const float4& v, int p) {
    return p == 0 ? v.x : p == 1 ? v.y : p == 2 ? v.z : v.w;
}
__device__ __forceinline__ int i4c(const int4& v, int p) {
    return p == 0 ? v.x : p == 1 ? v.y : p == 2 ? v.z : v.w;
}

// ---------------------------------------------------------------------------
// K1: kernel-dice sums, pos/neg counts (scalar pipe), min negative logit,
// segment sums (cnt_k, cnt_t via ballot; sum_k via predicated FMA).
// No histogram, no per-pixel atomics.
// ---------------------------------------------------------------------------
__global__ __launch_bounds__(256)
void k1_main(const float4* __restrict__ Tl, const float4* __restrict__ Kl,
             const float4* __restrict__ Fv, const float4* __restrict__ Gt,
             const float4* __restrict__ Gk, const float4* __restrict__ Tm,
             const int4* __restrict__ Ltk, const int4* __restrict__ Lkk,
             float* __restrict__ k1s, unsigned* __restrict__ minkeyinv) {
    const int b = blockIdx.y;
    const int tid = threadIdx.x;
    const long base4 = (long)b * HW4;
    const long f04 = (long)b * NCH * HW4;

    float racc[35];                 // 0..2 dice, 3.. sum_k[8][4]
#pragma unroll
    for (int j = 0; j < 35; j++) racc[j] = 0.f;
    float vmin = INFINITY;
    unsigned cpos = 0, cneg = 0;
    unsigned ck[8] = {0, 0, 0, 0, 0, 0, 0, 0};
    unsigned ct[8] = {0, 0, 0, 0, 0, 0, 0, 0};

#pragma unroll
    for (int it = 0; it < 2; ++it) {
        const int i4 = blockIdx.x * 512 + it * 256 + tid;
        const float4 tl4 = Tl[base4 + i4];
        const float4 kl4 = Kl[base4 + i4];
        const float4 gt4 = Gt[base4 + i4];
        const float4 gk4 = Gk[base4 + i4];
        const float4 tm4 = Tm[base4 + i4];
        const int4 ltk4 = Ltk[base4 + i4];
        const int4 lkk4 = Lkk[base4 + i4];
        const float4 F0v = Fv[f04 + i4];
        const float4 F1v = Fv[f04 + HW4 + i4];
        const float4 F2v = Fv[f04 + 2 * HW4 + i4];
        const float4 F3v = Fv[f04 + 3 * HW4 + i4];

#pragma unroll
        for (int p = 0; p < 4; p++) {
            float tl = f4c(tl4, p), kl = f4c(kl4, p);
            float gt = f4c(gt4, p), gk = f4c(gk4, p), m = f4c(tm4, p);
            int ltk_v = i4c(ltk4, p), lkk_v = i4c(lkk4, p);
            float F0 = f4c(F0v, p), F1 = f4c(F1v, p);
            float F2 = f4c(F2v, p), F3 = f4c(F3v, p);

            bool tm = m > 0.5f;
            bool selt = tl > 0.0f;      // sigmoid(x)>0.5 <=> x>0
            bool selk = kl > 0.0f;
            bool pos = gt > 0.5f;
            float km = (selt && tm) ? 1.f : 0.f;

            float pk = 1.f / (1.f + __expf(-kl));
            racc[0] = fmaf(pk * gk, km, racc[0]);
            racc[1] = fmaf(pk * pk, km, racc[1]);
            racc[2] = fmaf(gk * gk, km, racc[2]);

            cpos += __popcll(__ballot(pos && tm));
            cneg += __popcll(__ballot(!pos));
            vmin = fminf(vmin, pos ? INFINITY : tl);

            int lt = (selt && tm) ? ltk_v : 0;
            int lk = (selk && tm) ? lkk_v : 0;
#pragma unroll
            for (int s = 1; s <= 8; s++) {
                bool ek = (lk == s);
                ck[s - 1] += __popcll(__ballot(ek));
                ct[s - 1] += __popcll(__ballot(lt == s));
                float fek = ek ? 1.f : 0.f;
                racc[3 + (s - 1) * 4 + 0] = fmaf(fek, F0, racc[3 + (s - 1) * 4 + 0]);
                racc[3 + (s - 1) * 4 + 1] = fmaf(fek, F1, racc[3 + (s - 1) * 4 + 1]);
                racc[3 + (s - 1) * 4 + 2] = fmaf(fek, F2, racc[3 + (s - 1) * 4 + 2]);
                racc[3 + (s - 1) * 4 + 3] = fmaf(fek, F3, racc[3 + (s - 1) * 4 + 3]);
            }
        }
    }

#pragma unroll
    for (int j = 0; j < 35; j++) racc[j] = wred64(racc[j]);
    vmin = wredmin64(vmin);

    __shared__ float bacc[35];
    __shared__ float wminS[4];
    __shared__ unsigned cacc[4][18];
    const int wid = tid >> 6, lane = tid & 63;
    if (tid < 35) bacc[tid] = 0.f;
    __syncthreads();
    if (lane == 0) {
#pragma unroll
        for (int j = 0; j < 35; j++) atomicAdd(&bacc[j], racc[j]);
        wminS[wid] = vmin;
        cacc[wid][0] = cpos;
        cacc[wid][1] = cneg;
#pragma unroll
        for (int s = 0; s < 8; s++) {
            cacc[wid][2 + s] = ck[s];
            cacc[wid][10 + s] = ct[s];
        }
    }
    __syncthreads();
    if (tid < 35) {
        int g = (tid < 3) ? tid : (I_SUMK + tid - 3);
        atomicAdd(&k1s[b * N_K1 + g], bacc[tid]);
    }
    if (tid == 35) {
        float mn = fminf(fminf(wminS[0], wminS[1]), fminf(wminS[2], wminS[3]));
        if (mn < INFINITY) atomicMax(&minkeyinv[b], ~f2key(mn));
    }
    if (tid >= 64 && tid < 64 + 18) {
        int j = tid - 64;
        unsigned sum = cacc[0][j] + cacc[1][j] + cacc[2][j] + cacc[3][j];
        int g = (j == 0) ? I_POS : (j == 1) ? I_NEG
                : (j < 10) ? (I_CNTK + j - 2) : (I_CNTT + j - 10);
        atomicAdd(&k1s[b * N_K1 + g], (float)sum);
    }
}

// ---------------------------------------------------------------------------
// K2: per-batch OHEM decision. k = min(3*pos, neg). Fast paths:
//  pos==0 || k==0  -> thr = -inf (fallback mask = train_mask)
//  k == neg        -> thr = min negative logit (exact)
//  else            -> fb=0, k_rare does full radix select.
// ---------------------------------------------------------------------------
__global__ __launch_bounds__(64)
void k2_decide(const float* __restrict__ k1s, const unsigned* __restrict__ minkeyinv,
               float* thr, unsigned* kval, unsigned* fb) {
    const int b = threadIdx.x;
    if (b >= BATCH) return;
    unsigned pos = (unsigned)(k1s[b * N_K1 + I_POS] + 0.5f);
    unsigned neg = (unsigned)(k1s[b * N_K1 + I_NEG] + 0.5f);
    unsigned k = min(3u * pos, neg);
    kval[b] = k;
    if (pos == 0u || k == 0u) { thr[b] = -INFINITY; fb[b] = 1u; }
    else if (k == neg)        { thr[b] = key2f(~minkeyinv[b]); fb[b] = 1u; }
    else                      { fb[b] = 0u; }
}

// ---------------------------------------------------------------------------
// k_rare: general k-th-largest negative logit via 4-pass 8-bit radix select
// (one block per batch, LDS 256-bin histogram). Early-exits when fb set.
// ---------------------------------------------------------------------------
__global__ __launch_bounds__(256)
void k_rare(const float* __restrict__ Tl, const float* __restrict__ Gt,
            const unsigned* __restrict__ fb, const unsigned* __restrict__ kval,
            float* thr) {
    const int b = blockIdx.x;
    if (fb[b]) return;
    __shared__ unsigned hist[256];
    __shared__ unsigned sj, sprefix;
    const long base = (long)b * HW_N;
    if (threadIdx.x == 0) { sj = kval[b]; sprefix = 0u; }
    __syncthreads();
    for (int pass = 0; pass < 4; pass++) {
        const int shift = 24 - 8 * pass;
        if (threadIdx.x < 256) hist[threadIdx.x] = 0u;
        __syncthreads();
        const unsigned pref = sprefix;
        for (int i = threadIdx.x; i < HW_N; i += blockDim.x) {
            if (Gt[base + i] > 0.5f) continue;
            unsigned key = f2key(Tl[base + i]);
            if (pass == 0 || (key >> (shift + 8)) == pref)
                atomicAdd(&hist[(key >> shift) & 0xFFu], 1u);
        }
        __syncthreads();
        if (threadIdx.x == 0) {
            unsigned j = sj, cum = 0;
            for (int d = 255; d >= 0; --d) {
                cum += hist[d];
                if (cum >= j) {
                    sj = j - (cum - hist[d]);
                    sprefix = (pref << 8) | (unsigned)d;
                    break;
                }
            }
        }
        __syncthreads();
    }
    if (threadIdx.x == 0) thr[b] = key2f(sprefix);
}

// ---------------------------------------------------------------------------
// K5: text dice sums with OHEM mask + aggregation-loss segment sums.
// ---------------------------------------------------------------------------
__global__ __launch_bounds__(256)
void k5_textagg(const float4* __restrict__ Tl, const float4* __restrict__ Gt,
                const float4* __restrict__ Tm, const int4* __restrict__ Ltk,
                const float4* __restrict__ Fv, const float* __restrict__ k1s,
                const float* __restrict__ thr, float* __restrict__ k5s) {
    const int b = blockIdx.y;
    const int tid = threadIdx.x;
    __shared__ float Km[32];                      // [s-1][c], s=1..8
    if (tid < 32) {
        int s = tid >> 2, c = tid & 3;
        Km[tid] = k1s[b * N_K1 + I_SUMK + s * 4 + c] /
                  fmaxf(k1s[b * N_K1 + I_CNTK + s], 1.f);
    }
    __syncthreads();
    const float thr_b = thr[b];
    const long base4 = (long)b * HW4;
    const long f04 = (long)b * NCH * HW4;

    float r[N_K5];
#pragma unroll
    for (int j = 0; j < N_K5; j++) r[j] = 0.f;

#pragma unroll
    for (int it = 0; it < 2; ++it) {
        const int i4 = blockIdx.x * 512 + it * 256 + tid;
        const float4 tl4 = Tl[base4 + i4];
        const float4 gt4 = Gt[base4 + i4];
        const float4 tm4 = Tm[base4 + i4];
        const int4 ltk4 = Ltk[base4 + i4];
        const float4 F0v = Fv[f04 + i4];
        const float4 F1v = Fv[f04 + HW4 + i4];
        const float4 F2v = Fv[f04 + 2 * HW4 + i4];
        const float4 F3v = Fv[f04 + 3 * HW4 + i4];

#pragma unroll
        for (int p = 0; p < 4; p++) {
            float tl = f4c(tl4, p), gt = f4c(gt4, p), m = f4c(tm4, p);
            int ltk_v = i4c(ltk4, p);

            bool tm = m > 0.5f;
            bool pos = gt > 0.5f;
            float om = (((tl >= thr_b) || pos) && tm) ? 1.f : 0.f;
            float pt = 1.f / (1.f + __expf(-tl));
            r[0] = fmaf(pt * gt, om, r[0]);
            r[1] = fmaf(pt * pt, om, r[1]);
            r[2] = fmaf(gt * gt, om, r[2]);

            int lt = (tl > 0.f && tm) ? ltk_v : 0;
            if (lt > 0) {
                int kb = (lt - 1) * 4;
                float d0 = f4c(F0v, p) - Km[kb + 0];
                float d1 = f4c(F1v, p) - Km[kb + 1];
                float d2 = f4c(F2v, p) - Km[kb + 2];
                float d3 = f4c(F3v, p) - Km[kb + 3];
                float d = sqrtf(d0 * d0 + d1 * d1 + d2 * d2 + d3 * d3);
                float tt = fmaxf(d - 0.5f, 0.f);
                float pl = __logf(tt * tt + 1.f);
#pragma unroll
                for (int s = 1; s <= 8; s++)
                    r[3 + s] = fmaf((lt == s) ? 1.f : 0.f, pl, r[3 + s]);
            }
        }
    }

#pragma unroll
    for (int j = 0; j < N_K5; j++) r[j] = wred64(r[j]);

    __shared__ float bacc[N_K5];
    if (tid < N_K5) bacc[tid] = 0.f;
    __syncthreads();
    if ((tid & 63) == 0) {
#pragma unroll
        for (int j = 0; j < N_K5; j++) atomicAdd(&bacc[j], r[j]);
    }
    __syncthreads();
    if (tid < N_K5)
        atomicAdd(&k5s[b * N_K5 + tid], bacc[tid]);
}

// ---------------------------------------------------------------------------
// K6: final combine -> scalar loss. One block of 512 (wave b = batch b).
// ---------------------------------------------------------------------------
__global__ __launch_bounds__(512)
void k6_final(const float* __restrict__ k1s, const float* __restrict__ k5s,
              float* __restrict__ out) {
    const int tid = threadIdx.x;
    const int b = tid >> 6, lane = tid & 63;
    __shared__ float Km[BATCH][8][NCH];
    __shared__ float laS[BATCH], ldS[BATCH];

    if (tid < BATCH * 8 * NCH) {
        int bb = tid / 32, rem = tid % 32;
        int s = rem >> 2, c = rem & 3;
        Km[bb][s][c] = k1s[bb * N_K1 + I_SUMK + s * 4 + c] /
                       fmaxf(k1s[bb * N_K1 + I_CNTK + s], 1.f);
    }
    __syncthreads();

    const float* s1 = k1s + b * N_K1;
    const float* s5 = k5s + b * N_K5;

    // aggregation: lanes 1..8 = instances
    float aggs = 0.f, aggc = 0.f;
    if (lane >= 1 && lane <= 8) {
        float ctv = s1[I_CNTT + lane - 1], ckv = s1[I_CNTK + lane - 1];
        if (ctv > 0.f && ckv > 0.f) {
            aggs = s5[3 + lane] / fmaxf(ctv, 1.f);
            aggc = 1.f;
        }
    }
    // discrimination: 64 (i,j) pairs, i,j in 1..8 -> exactly one per lane
    float diss = 0.f, disc = 0.f;
    {
        int i = 1 + (lane >> 3), j = 1 + (lane & 7);
        if (i != j && s1[I_CNTK + i - 1] > 0.f && s1[I_CNTK + j - 1] > 0.f) {
            float d2 = 0.f;
#pragma unroll
            for (int c = 0; c < NCH; c++) {
                float df = Km[b][i - 1][c] - Km[b][j - 1][c];
                d2 += df * df;
            }
            float kd = sqrtf(d2);
            float t = fmaxf(3.0f - kd, 0.f);
            diss = logf(t * t + 1.f);
            disc = 1.f;
        }
    }
    aggs = wred64(aggs);
    aggc = wred64(aggc);
    diss = wred64(diss);
    disc = wred64(disc);
    if (lane == 0) {
        laS[b] = aggs / fmaxf(aggc, 1.f);
        ldS[b] = diss / fmaxf(disc, 1.f);
    }
    __syncthreads();

    if (tid == 0) {
        float Ltx = 0.f, Lk = 0.f, La = 0.f, Ld = 0.f;
        for (int bb = 0; bb < BATCH; bb++) {
            const float* a1 = k1s + bb * N_K1;
            const float* a5 = k5s + bb * N_K5;
            Lk += 1.f - 2.f * a1[I_AK] / ((a1[I_BK] + 1e-6f) + (a1[I_CK] + 1e-6f));
            Ltx += 1.f - 2.f * a5[0] / ((a5[1] + 1e-6f) + (a5[2] + 1e-6f));
            La += laS[bb];
            Ld += ldS[bb];
        }
        out[0] = Ltx / BATCH + 0.5f * (Lk / BATCH) + 0.25f * (La / BATCH + Ld / BATCH);
    }
}

// ---------------------------------------------------------------------------
extern "C" void kernel_launch(void* const* d_in, const int* in_sizes, int n_in,
                              void* d_out, int out_size, void* d_ws, size_t ws_size,
                              hipStream_t stream) {
    (void)in_sizes; (void)n_in; (void)out_size; (void)ws_size;
    const float4* Tl = (const float4*)d_in[0];
    const float4* Kl = (const float4*)d_in[1];
    const float4* Fv = (const float4*)d_in[2];
    const float4* Gt = (const float4*)d_in[3];
    const float4* Gk = (const float4*)d_in[4];
    const float4* Tm = (const float4*)d_in[5];
    const int4* Ltk = (const int4*)d_in[6];
    const int4* Lkk = (const int4*)d_in[7];
    float* out = (float*)d_out;

    float* k1s = (float*)d_ws;                       // B*53
    float* k5s = k1s + BATCH * N_K1;                 // B*12
    float* thr = k5s + BATCH * N_K5;                 // B
    unsigned* kval = (unsigned*)(thr + BATCH);       // B
    unsigned* fb = kval + BATCH;                     // B
    unsigned* minkeyinv = fb + BATCH;                // B

    size_t zero_bytes = (size_t)(BATCH * (N_K1 + N_K5) + 4 * BATCH) * 4;
    hipMemsetAsync(d_ws, 0, zero_bytes, stream);

    dim3 g(K1_BLOCKS, BATCH);   // 512 float4 per block, 2 per thread
    k1_main<<<g, 256, 0, stream>>>(Tl, Kl, Fv, Gt, Gk, Tm, Ltk, Lkk, k1s, minkeyinv);
    k2_decide<<<1, 64, 0, stream>>>(k1s, minkeyinv, thr, kval, fb);
    k_rare<<<BATCH, 256, 0, stream>>>((const float*)d_in[0], (const float*)d_in[3],
                                      fb, kval, thr);
    k5_textagg<<<g, 256, 0, stream>>>(Tl, Gt, Tm, Ltk, Fv, k1s, thr, k5s);
    k6_final<<<1, 512, 0, stream>>>(k1s, k5s, out);
}

// Round 4
// 86.967 us; speedup vs baseline: 2.3361x; 1.0768x over previous
//
#include <hip/hip_runtime.h>
#include <math.h>

#define BATCH 8
#define HW_N 409600          // 640*640
#define HW4 (HW_N / 4)       // 102400
#define NBLK 200             // blocks per batch for pixel kernels

// per-batch reduction slots
#define NP 56
#define J_AK   0             // kernel dice: sum pk*gk*km
#define J_BK   1             //              sum pk*pk*km
#define J_CK   2             //              sum gk*km   (gk^2=gk)
#define J_AT   3             // text dice:   sum pt over pos&tm
#define J_BTP  4             //              sum pt^2 over pos&tm
#define J_BTN  5             //              sum pt^2 over neg&tm (all-selected case)
#define J_CNTK 6             // +(s-1), s=1..8
#define J_CNTT 14            // +(s-1)
#define J_SUMK 22            // +(s-1)*4+c (32)
#define J_CPOS 54            // count(pos & tm)  == text dice c
#define J_CNEG 55            // count(!pos)

__device__ __forceinline__ unsigned f2key(float x) {
    unsigned u = __float_as_uint(x);
    return (u & 0x80000000u) ? ~u : (u | 0x80000000u);
}
__device__ __forceinline__ float key2f(unsigned k) {
    unsigned u = (k & 0x80000000u) ? (k & 0x7fffffffu) : ~k;
    return __uint_as_float(u);
}
__device__ __forceinline__ float wred64(float v) {
#pragma unroll
    for (int o = 32; o > 0; o >>= 1) v += __shfl_xor(v, o, 64);
    return v;
}
__device__ __forceinline__ float wredmin64(float v) {
#pragma unroll
    for (int o = 32; o > 0; o >>= 1) v = fminf(v, __shfl_xor(v, o, 64));
    return v;
}
__device__ __forceinline__ float f4c(const float4& v, int p) {
    return p == 0 ? v.x : p == 1 ? v.y : p == 2 ? v.z : v.w;
}
__device__ __forceinline__ int i4c(const int4& v, int p) {
    return p == 0 ? v.x : p == 1 ? v.y : p == 2 ? v.z : v.w;
}

// ---------------------------------------------------------------------------
// K1: single heavy pass. 6 register accumulators; segment sums/counts via
// block-LDS atomics (sparse lanes); counts pos/neg via ballot; min neg logit;
// packs {tm, selt, ltk} into a u8 plane for downstream kernels.
// Writes per-block partials (no global atomics).
// ---------------------------------------------------------------------------
__global__ __launch_bounds__(256)
void k1_main(const float4* __restrict__ Tl, const float4* __restrict__ Kl,
             const float4* __restrict__ Fv, const float4* __restrict__ Tm,
             const int4* __restrict__ Ltk, const int4* __restrict__ Lkk,
             float* __restrict__ part, unsigned* __restrict__ pk8,
             unsigned* __restrict__ minkeyinv) {
    const int b = blockIdx.y;
    const int tid = threadIdx.x;
    const long base4 = (long)b * HW4;
    const long f04 = (long)b * 4 * HW4;

    __shared__ float sK[32];             // sum_k [s-1][c]
    __shared__ unsigned cK[8], cT[8];
    __shared__ float bacc[6];
    __shared__ float wmin[4];
    __shared__ unsigned cP[4], cN[4];
    if (tid < 32) sK[tid] = 0.f;
    if (tid >= 32 && tid < 40) cK[tid - 32] = 0u;
    if (tid >= 40 && tid < 48) cT[tid - 40] = 0u;
    if (tid >= 48 && tid < 54) bacc[tid - 48] = 0.f;
    __syncthreads();

    float r0 = 0.f, r1 = 0.f, r2 = 0.f, r3 = 0.f, r4 = 0.f, r5 = 0.f;
    float vmin = INFINITY;
    unsigned cpos = 0, cneg = 0;

#pragma unroll
    for (int it = 0; it < 2; ++it) {
        const int i4 = blockIdx.x * 512 + it * 256 + tid;
        const float4 tl4 = Tl[base4 + i4];
        const float4 kl4 = Kl[base4 + i4];
        const float4 tm4 = Tm[base4 + i4];
        const int4 lt4 = Ltk[base4 + i4];
        const int4 lk4 = Lkk[base4 + i4];
        const float4 F0v = Fv[f04 + i4];
        const float4 F1v = Fv[f04 + HW4 + i4];
        const float4 F2v = Fv[f04 + 2 * HW4 + i4];
        const float4 F3v = Fv[f04 + 3 * HW4 + i4];
        unsigned pkw = 0;
#pragma unroll
        for (int p = 0; p < 4; ++p) {
            float tl = f4c(tl4, p), kl = f4c(kl4, p), m = f4c(tm4, p);
            int ltk = i4c(lt4, p), lkk = i4c(lk4, p);
            bool tm = m > 0.5f;
            bool selt = tl > 0.f;        // sigmoid(x)>0.5 <=> x>0
            bool selk = kl > 0.f;
            bool pos = ltk > 0;          // gt_text == (gt_text_key > 0)
            float gkf = (lkk > 0) ? 1.f : 0.f;
            float km = (selt && tm) ? 1.f : 0.f;
            float pkv = 1.f / (1.f + __expf(-kl));
            float ptv = 1.f / (1.f + __expf(-tl));
            r0 = fmaf(pkv * gkf, km, r0);
            r1 = fmaf(pkv * pkv, km, r1);
            r2 = fmaf(gkf, km, r2);
            float ptm = (pos && tm) ? 1.f : 0.f;
            float ntm = (!pos && tm) ? 1.f : 0.f;
            r3 = fmaf(ptv, ptm, r3);
            r4 = fmaf(ptv * ptv, ptm, r4);
            r5 = fmaf(ptv * ptv, ntm, r5);
            cpos += __popcll(__ballot(pos && tm));
            cneg += __popcll(__ballot(!pos));
            vmin = fminf(vmin, pos ? INFINITY : tl);
            int lt = (selt && tm) ? ltk : 0;
            int lk = (selk && tm) ? lkk : 0;
            if (lk > 0) {
                atomicAdd(&sK[(lk - 1) * 4 + 0], f4c(F0v, p));
                atomicAdd(&sK[(lk - 1) * 4 + 1], f4c(F1v, p));
                atomicAdd(&sK[(lk - 1) * 4 + 2], f4c(F2v, p));
                atomicAdd(&sK[(lk - 1) * 4 + 3], f4c(F3v, p));
                atomicAdd(&cK[lk - 1], 1u);
            }
            if (lt > 0) atomicAdd(&cT[lt - 1], 1u);
            unsigned byte = (tm ? 1u : 0u) | (selt ? 2u : 0u) | ((unsigned)ltk << 2);
            pkw |= byte << (8 * p);
        }
        pk8[base4 + i4] = pkw;
    }

    r0 = wred64(r0); r1 = wred64(r1); r2 = wred64(r2);
    r3 = wred64(r3); r4 = wred64(r4); r5 = wred64(r5);
    vmin = wredmin64(vmin);
    const int wid = tid >> 6, lane = tid & 63;
    if (lane == 0) {
        atomicAdd(&bacc[0], r0); atomicAdd(&bacc[1], r1); atomicAdd(&bacc[2], r2);
        atomicAdd(&bacc[3], r3); atomicAdd(&bacc[4], r4); atomicAdd(&bacc[5], r5);
        wmin[wid] = vmin; cP[wid] = cpos; cN[wid] = cneg;
    }
    __syncthreads();

    float v = 0.f; bool w = true;
    if (tid < 6) v = bacc[tid];
    else if (tid < 14) v = (float)cK[tid - 6];
    else if (tid < 22) v = (float)cT[tid - 14];
    else if (tid < 54) v = sK[tid - 22];
    else if (tid == 54) v = (float)(cP[0] + cP[1] + cP[2] + cP[3]);
    else if (tid == 55) v = (float)(cN[0] + cN[1] + cN[2] + cN[3]);
    else w = false;
    if (w) part[((size_t)b * NP + tid) * NBLK + blockIdx.x] = v;
    if (tid == 56) {
        float mn = fminf(fminf(wmin[0], wmin[1]), fminf(wmin[2], wmin[3]));
        if (mn < INFINITY) atomicMax(&minkeyinv[b], ~f2key(mn));
    }
}

// ---------------------------------------------------------------------------
// K1R: reduce per-block partials (coalesced: part[b][j][blk]), compute kernel
// means, and make the OHEM decision (fused).
// ---------------------------------------------------------------------------
__global__ __launch_bounds__(256)
void k1_reduce(const float* __restrict__ part, const unsigned* __restrict__ minkeyinv,
               float* __restrict__ k1s, float* __restrict__ kms,
               float* __restrict__ thr, unsigned* __restrict__ kval,
               unsigned* __restrict__ fb) {
    const int b = blockIdx.x;
    const int tid = threadIdx.x, wid = tid >> 6, lane = tid & 63;
    __shared__ float ss[NP];
    __shared__ unsigned sfb;
    for (int j = wid; j < NP; j += 4) {
        const float* p = part + ((size_t)b * NP + j) * NBLK;
        float v = 0.f;
        for (int i = lane; i < NBLK; i += 64) v += p[i];
        v = wred64(v);
        if (lane == 0) ss[j] = v;
    }
    __syncthreads();
    if (tid == 0) {
        unsigned pos = (unsigned)(ss[J_CPOS] + 0.5f);
        unsigned neg = (unsigned)(ss[J_CNEG] + 0.5f);
        unsigned k = min(3u * pos, neg);
        kval[b] = k;
        unsigned f;
        if (pos == 0u || k == 0u) { thr[b] = -INFINITY; f = 1u; }
        else if (k == neg)        { thr[b] = key2f(~minkeyinv[b]); f = 1u; }
        else                      { f = 0u; }   // rare: radix path
        fb[b] = f; sfb = f;
    }
    __syncthreads();
    if (tid < NP)
        k1s[b * NP + tid] = (tid == J_BTN && sfb == 0u) ? 0.f : ss[tid];
    if (tid >= 64 && tid < 96) {
        int t = tid - 64, s = t >> 2;
        kms[b * 32 + t] = ss[J_SUMK + t] / fmaxf(ss[J_CNTK + s], 1.f);
    }
}

// ---------------------------------------------------------------------------
// K_RARE: exact k-th-largest negative logit via 4-pass radix select.
// Early-exits in the common (fb=1) case.
// ---------------------------------------------------------------------------
__global__ __launch_bounds__(256)
void k_rare(const float* __restrict__ Tl, const unsigned char* __restrict__ pk8,
            const unsigned* __restrict__ fb, const unsigned* __restrict__ kval,
            float* __restrict__ thr) {
    const int b = blockIdx.x;
    if (fb[b]) return;
    __shared__ unsigned hist[256];
    __shared__ unsigned sj, spre;
    const long base = (long)b * HW_N;
    if (threadIdx.x == 0) { sj = kval[b]; spre = 0u; }
    __syncthreads();
    for (int pass = 0; pass < 4; ++pass) {
        const int shift = 24 - 8 * pass;
        hist[threadIdx.x] = 0u;
        __syncthreads();
        const unsigned pref = spre;
        for (int i = threadIdx.x; i < HW_N; i += 256) {
            if (((pk8[base + i] >> 2) & 0xFu) != 0u) continue;   // pos pixel
            unsigned key = f2key(Tl[base + i]);
            if (pass == 0 || (key >> (shift + 8)) == pref)
                atomicAdd(&hist[(key >> shift) & 0xFFu], 1u);
        }
        __syncthreads();
        if (threadIdx.x == 0) {
            unsigned j = sj, cum = 0;
            for (int d = 255; d >= 0; --d) {
                cum += hist[d];
                if (cum >= j) {
                    sj = j - (cum - hist[d]);
                    spre = (pref << 8) | (unsigned)d;
                    break;
                }
            }
        }
        __syncthreads();
    }
    if (threadIdx.x == 0) thr[b] = key2f(spre);
}

// ---------------------------------------------------------------------------
// K_NEGFIX: rare path only — recompute b_neg = sum pt^2 over selected negs.
// ---------------------------------------------------------------------------
__global__ __launch_bounds__(256)
void k_negfix(const float4* __restrict__ Tl, const unsigned* __restrict__ pk8,
              const unsigned* __restrict__ fb, const float* __restrict__ thr,
              float* __restrict__ k1s) {
    const int b = blockIdx.y;
    if (fb[b]) return;
    const int tid = threadIdx.x;
    const long base4 = (long)b * HW4;
    const float tb = thr[b];
    float acc = 0.f;
#pragma unroll
    for (int it = 0; it < 2; ++it) {
        const int i4 = blockIdx.x * 512 + it * 256 + tid;
        const float4 tl4 = Tl[base4 + i4];
        const unsigned pkw = pk8[base4 + i4];
#pragma unroll
        for (int p = 0; p < 4; ++p) {
            unsigned byte = (pkw >> (8 * p)) & 0xFFu;
            bool tm = byte & 1u;
            bool neg = ((byte >> 2) & 0xFu) == 0u;
            float tl = f4c(tl4, p);
            if (neg && tm && tl >= tb) {
                float pt = 1.f / (1.f + __expf(-tl));
                acc = fmaf(pt, pt, acc);
            }
        }
    }
    acc = wred64(acc);
    __shared__ float wacc[4];
    if ((tid & 63) == 0) wacc[tid >> 6] = acc;
    __syncthreads();
    if (tid == 0)
        atomicAdd(&k1s[b * NP + J_BTN], wacc[0] + wacc[1] + wacc[2] + wacc[3]);
}

// ---------------------------------------------------------------------------
// K5: aggregation-loss pass — reads only Fv + packed plane. sum_l via
// block-LDS atomics, 8 global atomics per block.
// ---------------------------------------------------------------------------
__global__ __launch_bounds__(256)
void k5_agg(const unsigned* __restrict__ pk8, const float4* __restrict__ Fv,
            const float* __restrict__ kms, float* __restrict__ sl) {
    const int b = blockIdx.y;
    const int tid = threadIdx.x;
    __shared__ float Kml[32];
    __shared__ float sL[8];
    if (tid < 32) Kml[tid] = kms[b * 32 + tid];
    if (tid >= 32 && tid < 40) sL[tid - 32] = 0.f;
    __syncthreads();
    const long base4 = (long)b * HW4;
    const long f04 = (long)b * 4 * HW4;
#pragma unroll
    for (int it = 0; it < 2; ++it) {
        const int i4 = blockIdx.x * 512 + it * 256 + tid;
        const unsigned pkw = pk8[base4 + i4];
        const float4 F0v = Fv[f04 + i4];
        const float4 F1v = Fv[f04 + HW4 + i4];
        const float4 F2v = Fv[f04 + 2 * HW4 + i4];
        const float4 F3v = Fv[f04 + 3 * HW4 + i4];
#pragma unroll
        for (int p = 0; p < 4; ++p) {
            unsigned byte = (pkw >> (8 * p)) & 0xFFu;
            int lt = ((byte & 3u) == 3u) ? (int)((byte >> 2) & 0xFu) : 0;
            if (lt > 0) {
                int kb = (lt - 1) * 4;
                float d0 = f4c(F0v, p) - Kml[kb + 0];
                float d1 = f4c(F1v, p) - Kml[kb + 1];
                float d2 = f4c(F2v, p) - Kml[kb + 2];
                float d3 = f4c(F3v, p) - Kml[kb + 3];
                float d = sqrtf(fmaf(d0, d0, fmaf(d1, d1, fmaf(d2, d2, d3 * d3))));
                float t = fmaxf(d - 0.5f, 0.f);
                atomicAdd(&sL[lt - 1], __logf(fmaf(t, t, 1.f)));
            }
        }
    }
    __syncthreads();
    if (tid < 8) atomicAdd(&sl[b * 8 + tid], sL[tid]);
}

// ---------------------------------------------------------------------------
// K6: final combine -> scalar loss.
// ---------------------------------------------------------------------------
__global__ __launch_bounds__(512)
void k6_final(const float* __restrict__ k1s, const float* __restrict__ kms,
              const float* __restrict__ sl, float* __restrict__ out) {
    const int tid = threadIdx.x;
    const int b = tid >> 6, lane = tid & 63;
    __shared__ float KmS[BATCH * 32];
    __shared__ float laS[BATCH], ldS[BATCH];
    if (tid < BATCH * 32) KmS[tid] = kms[tid];
    __syncthreads();
    const float* s1 = k1s + b * NP;

    float aggs = 0.f, aggc = 0.f;
    if (lane >= 1 && lane <= 8) {
        float ctv = s1[J_CNTT + lane - 1], ckv = s1[J_CNTK + lane - 1];
        if (ctv > 0.f && ckv > 0.f) {
            aggs = sl[b * 8 + lane - 1] / fmaxf(ctv, 1.f);
            aggc = 1.f;
        }
    }
    float diss = 0.f, disc = 0.f;
    {
        int i = 1 + (lane >> 3), j = 1 + (lane & 7);
        if (i != j && s1[J_CNTK + i - 1] > 0.f && s1[J_CNTK + j - 1] > 0.f) {
            float d2 = 0.f;
#pragma unroll
            for (int c = 0; c < 4; ++c) {
                float df = KmS[b * 32 + (i - 1) * 4 + c] - KmS[b * 32 + (j - 1) * 4 + c];
                d2 = fmaf(df, df, d2);
            }
            float kd = sqrtf(d2);
            float t = fmaxf(3.f - kd, 0.f);
            diss = logf(t * t + 1.f);
            disc = 1.f;
        }
    }
    aggs = wred64(aggs); aggc = wred64(aggc);
    diss = wred64(diss); disc = wred64(disc);
    if (lane == 0) {
        laS[b] = aggs / fmaxf(aggc, 1.f);
        ldS[b] = diss / fmaxf(disc, 1.f);
    }
    __syncthreads();
    if (tid == 0) {
        float Lt = 0.f, Lk = 0.f, La = 0.f, Ld = 0.f;
        for (int bb = 0; bb < BATCH; ++bb) {
            const float* a = k1s + bb * NP;
            Lk += 1.f - 2.f * a[J_AK] / ((a[J_BK] + 1e-6f) + (a[J_CK] + 1e-6f));
            float bt = a[J_BTP] + a[J_BTN];
            Lt += 1.f - 2.f * a[J_AT] / ((bt + 1e-6f) + (a[J_CPOS] + 1e-6f));
            La += laS[bb]; Ld += ldS[bb];
        }
        out[0] = Lt / BATCH + 0.5f * (Lk / BATCH) + 0.25f * (La / BATCH + Ld / BATCH);
    }
}

// ---------------------------------------------------------------------------
extern "C" void kernel_launch(void* const* d_in, const int* in_sizes, int n_in,
                              void* d_out, int out_size, void* d_ws, size_t ws_size,
                              hipStream_t stream) {
    (void)in_sizes; (void)n_in; (void)out_size; (void)ws_size;
    const float4* Tl = (const float4*)d_in[0];   // pre_text_logits
    const float4* Kl = (const float4*)d_in[1];   // pre_kernel_logits
    const float4* Fv = (const float4*)d_in[2];   // similarity_vector [B,C,H,W]
    const float4* Tm = (const float4*)d_in[5];   // train_mask
    const int4* Ltk = (const int4*)d_in[6];      // gt_text_key
    const int4* Lkk = (const int4*)d_in[7];      // gt_kernel_key
    float* out = (float*)d_out;

    // ws layout (4B units): [sl 64][minkeyinv 8][thr 8][kval 8][fb 8]
    //                       [k1s 448][kms 256][part 89600][pk8 819200]
    float* sl = (float*)d_ws;                          // 8*8
    unsigned* minkeyinv = (unsigned*)(sl + 64);        // 8
    float* thr = (float*)(minkeyinv + 8);              // 8
    unsigned* kval = (unsigned*)(thr + 8);             // 8
    unsigned* fb = kval + 8;                           // 8
    float* k1s = (float*)(fb + 8);                     // 8*56
    float* kms = k1s + BATCH * NP;                     // 8*32
    float* part = kms + BATCH * 32;                    // 8*56*200
    unsigned* pk8 = (unsigned*)(part + (size_t)BATCH * NP * NBLK);  // 8*HW4 u32

    hipMemsetAsync(d_ws, 0, (64 + 8) * 4, stream);     // sl + minkeyinv

    dim3 g(NBLK, BATCH);
    k1_main<<<g, 256, 0, stream>>>(Tl, Kl, Fv, Tm, Ltk, Lkk, part, pk8, minkeyinv);
    k1_reduce<<<BATCH, 256, 0, stream>>>(part, minkeyinv, k1s, kms, thr, kval, fb);
    k_rare<<<BATCH, 256, 0, stream>>>((const float*)d_in[0],
                                      (const unsigned char*)pk8, fb, kval, thr);
    k_negfix<<<g, 256, 0, stream>>>(Tl, pk8, fb, thr, k1s);
    k5_agg<<<g, 256, 0, stream>>>(pk8, Fv, kms, sl);
    k6_final<<<1, 512, 0, stream>>>(k1s, kms, sl, out);
}